// Round 5
// baseline (277.641 us; speedup 1.0000x reference)
//
#include <hip/hip_runtime.h>
#include <hip/hip_bf16.h>
#include <stdint.h>

#define D_IN   128
#define NPOLY  8256           // D*(D+1)/2
#define KDIM   8384           // D + NPOLY
#define B_ROWS 8192
#define N_COLS 512

// ---- workspace layout (bytes) ----
#define TBL_OFF   0
#define TBL_BYTES (NPOLY * 2)
#define WBF_OFF   (TBL_OFF + TBL_BYTES)
#define WBF_BYTES ((size_t)N_COLS * KDIM * 2)         // 8,585,216
#define FEA_OFF   (WBF_OFF + WBF_BYTES)
#define FEA_BYTES ((size_t)B_ROWS * KDIM * 2)         // 137,363,456
#define WS_NEED   (FEA_OFF + FEA_BYTES)               // ~146 MB

typedef __attribute__((ext_vector_type(8))) short    bf16x8_t;
typedef __attribute__((ext_vector_type(8))) float    f32x8_t;
typedef __attribute__((ext_vector_type(4))) float    f32x4_t;

__device__ __forceinline__ uint16_t f2bf(float f) {
  union { float f; uint32_t u; } c; c.f = f;
  uint32_t u = c.u;
  uint32_t r = (u + 0x7fffu + ((u >> 16) & 1u)) >> 16;   // RNE
  return (uint16_t)r;
}

__device__ __forceinline__ void async_load16(void* lds_dst, const void* g_src) {
  __builtin_amdgcn_global_load_lds(
      (const __attribute__((address_space(1))) void*)g_src,
      (__attribute__((address_space(3))) void*)lds_dst,
      16, 0, 0);
}

// ---------------- fused prep: init_out | wconv | build_table ----------------
#define NB_INIT 4096
#define NB_WCNV 2096
#define NB_TBL  33
__global__ void prep(const float* __restrict__ w, const float* __restrict__ bias,
                     float* __restrict__ out, uint16_t* __restrict__ wb,
                     uint16_t* __restrict__ tbl) {
  int blk = blockIdx.x;
  int tid = threadIdx.x;
  if (blk < NB_INIT) {
    int idx = blk * 256 + tid;                         // float4 index
    f32x4_t bv = *(const f32x4_t*)(bias + ((idx * 4) & (N_COLS - 1)));
    *(f32x4_t*)(out + (size_t)idx * 4) = bv;
  } else if (blk < NB_INIT + NB_WCNV) {
    int g = (blk - NB_INIT) * 256 + tid;               // group of 8
    f32x8_t v = *(const f32x8_t*)(w + (size_t)g * 8);
    bf16x8_t o;
#pragma unroll
    for (int e = 0; e < 8; ++e) o[e] = (short)f2bf(v[e]);
    *(bf16x8_t*)(wb + (size_t)g * 8) = o;
  } else {
    int p = (blk - NB_INIT - NB_WCNV) * 256 + tid;
    if (p >= NPOLY) return;
    float t = 66049.0f - 8.0f * (float)p;              // 257^2 - 8p
    int i = (int)((257.0f - sqrtf(t)) * 0.5f);
    if (i < 0) i = 0; if (i > 127) i = 127;
    while (i < 127 && ((i + 1) * (257 - (i + 1))) / 2 <= p) ++i;
    while (i > 0 && (i * (257 - i)) / 2 > p) --i;
    int j = i + (p - (i * (257 - i)) / 2);
    tbl[p] = (uint16_t)((i << 8) | j);
  }
}

// ---------------- feature expansion -> bf16 feats [B_ROWS][KDIM] ----------------
__global__ __launch_bounds__(256) void feat_gen(
    const float* __restrict__ x, const uint16_t* __restrict__ tbl,
    uint16_t* __restrict__ feats) {
  __shared__ float xs[D_IN];
  __shared__ __align__(16) uint16_t pr[KDIM];
  const int b = blockIdx.x;
  const int tid = threadIdx.x;
  if (tid < D_IN) {
    float v = x[(size_t)b * D_IN + tid];
    xs[tid] = v;
    pr[tid] = f2bf(v);
  }
  __syncthreads();
#pragma unroll 4
  for (int p = tid; p < NPOLY; p += 256) {
    uint32_t t = tbl[p];
    pr[D_IN + p] = f2bf(xs[t >> 8] * xs[t & 255u]);
  }
  __syncthreads();
  const bf16x8_t* src = (const bf16x8_t*)pr;
  bf16x8_t* dst = (bf16x8_t*)(feats + (size_t)b * KDIM);
  for (int g = tid; g < KDIM / 8; g += 256) dst[g] = src[g];
}

// ---------------- bf16 MFMA GEMM: out += feats @ W^T ----------------
// BM=BN=128, BK=64, 4 waves (2x2), split-K=3 (grid 768, 3 blocks/CU).
// A staged via global_load_lds (pre-swizzled source, 16KB, 2-barrier loop);
// W-fragments DIRECT from global (row-major K-contiguous == B-fragment
// layout). XCD-bijective 1D decode keeps one A row-band per XCD.
#define BMT 128
#define BNT 128
#define BKT 64
#define KSTEPS 131   // 8384/64
#define KP     44    // 44+44+43

__global__ __launch_bounds__(256, 3) void gemm_poly(
    const uint16_t* __restrict__ A,   // feats bf16 [B_ROWS][KDIM]
    const uint16_t* __restrict__ W,   // bf16 [N_COLS][KDIM]
    float* __restrict__ out) {
  __shared__ __align__(16) uint16_t sA[BMT * BKT];   // 16 KB

  const int tid  = threadIdx.x;
  const int lane = tid & 63;
  const int wv   = tid >> 6;
  const int wr   = wv >> 1;     // wave row (0..1)
  const int wc   = wv & 1;      // wave col (0..1)
  const int hi   = lane >> 4;   // 0..3
  const int lr   = lane & 15;

  // XCD-bijective decode: 768 blocks, 96/XCD; consecutive slots on an XCD
  // sweep (y,z) within the same x => shared A row-band in that XCD's L2.
  int bid = blockIdx.x;
  int lin = (bid & 7) * 96 + (bid >> 3);
  int bx  = lin / 12;
  int rem = lin - bx * 12;
  int by  = rem / 3;
  int bz  = rem - by * 3;

  const int b0  = bx * BMT;
  const int n0  = by * BNT;
  const int kt0 = bz * KP;
  const int kt1 = (bz == 2) ? KSTEPS : kt0 + KP;

  // sA staging geometry: linear LDS offset L = q*4096 + tid*16 -> (row, cb)
  int rowq[4], cbxq[4];
#pragma unroll
  for (int q = 0; q < 4; ++q) {
    int L = q * 4096 + tid * 16;
    int row = L >> 7;          // 128 B per row
    int cb  = L & 127;
    rowq[q] = row;
    cbxq[q] = cb ^ ((row & 7) << 4);   // inverse-swizzled source chunk
  }

  // A-fragment LDS byte offsets (same XOR on read)
  int offA[4][2];
#pragma unroll
  for (int f = 0; f < 4; ++f) {
    int rowA = wr * 64 + f * 16 + lr;
#pragma unroll
    for (int kh = 0; kh < 2; ++kh) {
      int kb = kh * 64 + hi * 16;
      offA[f][kh] = rowA * 128 + (kb ^ ((rowA & 7) << 4));
    }
  }

  // W-fragment global byte offsets — INCLUDES n0 (round-4 bug: it was missing)
  uint32_t wOff[4];
#pragma unroll
  for (int nf = 0; nf < 4; ++nf) {
    int rowW = n0 + wc * 64 + nf * 16 + lr;            // global W row
    wOff[nf] = (uint32_t)rowW * (KDIM * 2) + (uint32_t)hi * 16;
  }

  f32x4_t acc[4][4];
#pragma unroll
  for (int mf = 0; mf < 4; ++mf)
#pragma unroll
    for (int nf = 0; nf < 4; ++nf) {
      f32x4_t z = {0.f, 0.f, 0.f, 0.f};
      acc[mf][nf] = z;
    }

  const char* Ab = (const char*)A;
  const char* Wb = (const char*)W;

#define STAGE(kt)                                                              \
  {                                                                            \
    _Pragma("unroll")                                                          \
    for (int q = 0; q < 4; ++q) {                                              \
      const char* srcA =                                                       \
          Ab + ((size_t)(b0 + rowq[q]) * KDIM + (kt) * BKT) * 2 + cbxq[q];     \
      async_load16((char*)sA + q * 4096 + tid * 16, srcA);                     \
    }                                                                          \
  }

  STAGE(kt0);
  for (int kt = kt0; kt < kt1; ++kt) {
    __syncthreads();   // staging drained, sA visible
    const char* wk = Wb + (uint32_t)kt * 128;
    bf16x8_t b[4][2];
#pragma unroll
    for (int nf = 0; nf < 4; ++nf) {
      b[nf][0] = *(const bf16x8_t*)(wk + wOff[nf]);
      b[nf][1] = *(const bf16x8_t*)(wk + wOff[nf] + 64);
    }
    bf16x8_t a[4][2];
#pragma unroll
    for (int mf = 0; mf < 4; ++mf)
#pragma unroll
      for (int kh = 0; kh < 2; ++kh)
        a[mf][kh] = *(const bf16x8_t*)((const char*)sA + offA[mf][kh]);
    __builtin_amdgcn_s_setprio(1);
#pragma unroll
    for (int mf = 0; mf < 4; ++mf)
#pragma unroll
      for (int nf = 0; nf < 4; ++nf) {
        acc[mf][nf] = __builtin_amdgcn_mfma_f32_16x16x32_bf16(
            a[mf][0], b[nf][0], acc[mf][nf], 0, 0, 0);
        acc[mf][nf] = __builtin_amdgcn_mfma_f32_16x16x32_bf16(
            a[mf][1], b[nf][1], acc[mf][nf], 0, 0, 0);
      }
    __builtin_amdgcn_s_setprio(0);
    __syncthreads();   // all reads of sA done before next overwrite
    if (kt + 1 < kt1) STAGE(kt + 1);
  }

  // epilogue: C/D layout col=lane&15, row=(lane>>4)*4+reg
#pragma unroll
  for (int mf = 0; mf < 4; ++mf) {
    int row = b0 + wr * 64 + mf * 16 + hi * 4;
#pragma unroll
    for (int nf = 0; nf < 4; ++nf) {
      int col = n0 + wc * 64 + nf * 16 + lr;
#pragma unroll
      for (int r = 0; r < 4; ++r) {
        atomicAdd(&out[(size_t)(row + r) * N_COLS + col], acc[mf][nf][r]);
      }
    }
  }
#undef STAGE
}

// ---------------- naive fallback (only if ws too small) ----------------
__global__ void naive_poly(const float* __restrict__ x, const float* __restrict__ w,
                           const float* __restrict__ bias, float* __restrict__ out) {
  size_t o = (size_t)blockIdx.x * 256 + threadIdx.x;
  if (o >= (size_t)B_ROWS * N_COLS) return;
  int n = (int)(o >> 13);
  int b = (int)(o & (B_ROWS - 1));
  const float* xr = x + (size_t)b * D_IN;
  const float* wr = w + (size_t)n * KDIM;
  float acc = bias[n];
  for (int k = 0; k < D_IN; ++k) acc += wr[k] * xr[k];
  int p = D_IN;
  for (int i = 0; i < D_IN; ++i) {
    float xi = xr[i];
    for (int j = i; j < D_IN; ++j) acc += wr[p++] * xi * xr[j];
  }
  out[(size_t)b * N_COLS + n] = acc;
}

extern "C" void kernel_launch(void* const* d_in, const int* in_sizes, int n_in,
                              void* d_out, int out_size, void* d_ws, size_t ws_size,
                              hipStream_t stream) {
  const float* x    = (const float*)d_in[0];
  const float* w    = (const float*)d_in[1];
  const float* bias = (const float*)d_in[2];
  float* out = (float*)d_out;

  if (ws_size < WS_NEED) {   // safety net: correct but slow
    naive_poly<<<(B_ROWS * N_COLS) / 256, 256, 0, stream>>>(x, w, bias, out);
    return;
  }

  char* ws = (char*)d_ws;
  uint16_t* tbl = (uint16_t*)(ws + TBL_OFF);
  uint16_t* wb  = (uint16_t*)(ws + WBF_OFF);
  uint16_t* fe  = (uint16_t*)(ws + FEA_OFF);

  prep<<<NB_INIT + NB_WCNV + NB_TBL, 256, 0, stream>>>(w, bias, out, wb, tbl);
  feat_gen<<<B_ROWS, 256, 0, stream>>>(x, tbl, fe);
  gemm_poly<<<768, 256, 0, stream>>>(fe, wb, out);
}

// Round 6
// 200.556 us; speedup vs baseline: 1.3844x; 1.3844x over previous
//
#include <hip/hip_runtime.h>
#include <hip/hip_bf16.h>
#include <stdint.h>

#define D_IN   128
#define NPOLY  8256           // D*(D+1)/2
#define KDIM   8384           // D + NPOLY
#define B_ROWS 8192
#define N_COLS 512

// ---- workspace layout (bytes) ----
#define WBF_OFF   0
#define WBF_BYTES ((size_t)N_COLS * KDIM * 2)         // 8,585,216
#define FEA_OFF   WBF_BYTES
#define FEA_BYTES ((size_t)B_ROWS * KDIM * 2)         // 137,363,456
#define WS_NEED   (FEA_OFF + FEA_BYTES)               // ~146 MB

typedef __attribute__((ext_vector_type(8))) short    bf16x8_t;
typedef __attribute__((ext_vector_type(8))) float    f32x8_t;
typedef __attribute__((ext_vector_type(4))) float    f32x4_t;
typedef __attribute__((ext_vector_type(4))) uint32_t u32x4_t;

// one-instruction packed f32x2 -> bf16x2 (RNE on gfx950)
__device__ __forceinline__ uint32_t pk2(float lo, float hi) {
  uint32_t r;
  asm("v_cvt_pk_bf16_f32 %0, %1, %2" : "=v"(r) : "v"(lo), "v"(hi));
  return r;
}

__device__ __forceinline__ void async_load16(void* lds_dst, const void* g_src) {
  __builtin_amdgcn_global_load_lds(
      (const __attribute__((address_space(1))) void*)g_src,
      (__attribute__((address_space(3))) void*)lds_dst,
      16, 0, 0);
}

// ---------------- fused prep: feat_gen (2 rows/blk) | init_out | wconv -------
// No tbl: pair indices from exact closed form + wrap walk.
#define NB_FEAT 4096   // 2 rows each
#define NB_INIT 4096   // out bias-init, float4
#define NB_WCNV 2096   // W f32->bf16, x8
__global__ __launch_bounds__(256) void fused_prep(
    const float* __restrict__ x, const float* __restrict__ w,
    const float* __restrict__ bias, float* __restrict__ out,
    uint16_t* __restrict__ wb, uint16_t* __restrict__ feats) {
  __shared__ float xs[2][D_IN];
  __shared__ __align__(16) uint16_t pr[2][KDIM];
  const int blk = blockIdx.x;
  const int tid = threadIdx.x;

  if (blk < NB_FEAT) {
    const int r0 = blk * 2;
    // load both rows (256 threads = 2x128 floats, one coalesced kB)
    xs[tid >> 7][tid & 127] = x[(size_t)r0 * D_IN + tid];
    __syncthreads();
    // head: bf16(x) for both rows
    if (tid < 32) {
      int row = tid >> 4, c8 = (tid & 15) * 8;
      u32x4_t o;
#pragma unroll
      for (int h = 0; h < 4; ++h)
        o[h] = pk2(xs[row][c8 + 2 * h], xs[row][c8 + 2 * h + 1]);
      *(u32x4_t*)&pr[row][c8] = o;
    }
    // poly: 1032 groups of 8 consecutive p
    for (int it = 0; it < 5; ++it) {
      int g = tid + it * 256;
      if (g >= NPOLY / 8) break;
      int p0 = 8 * g;
      float t = 66049.0f - 8.0f * (float)p0;           // (257-2i)^2 at seg starts
      int i = (int)((257.0f - sqrtf(t)) * 0.5f);
      while (i > 0 && (i * (257 - i)) / 2 > p0) --i;   // safety fixup (<=1 iter)
      while (i < 127 && ((i + 1) * (257 - (i + 1))) / 2 <= p0) ++i;
      int j = i + (p0 - (i * (257 - i)) / 2);
      float xi0 = xs[0][i], xi1 = xs[1][i];
      float q0[8], q1[8];
#pragma unroll
      for (int e = 0; e < 8; ++e) {
        q0[e] = xi0 * xs[0][j];
        q1[e] = xi1 * xs[1][j];
        if (e < 7) {                     // advance p by one
          if (j == 127) { ++i; j = i; xi0 = xs[0][i]; xi1 = xs[1][i]; }
          else ++j;
        }
      }
      u32x4_t o0, o1;
#pragma unroll
      for (int h = 0; h < 4; ++h) {
        o0[h] = pk2(q0[2 * h], q0[2 * h + 1]);
        o1[h] = pk2(q1[2 * h], q1[2 * h + 1]);
      }
      *(u32x4_t*)&pr[0][D_IN + p0] = o0;               // byte 256+16g: aligned
      *(u32x4_t*)&pr[1][D_IN + p0] = o1;
    }
    __syncthreads();
    // vectorized copy-out: 2 x 1048 b128 groups
    uint16_t* d0 = feats + (size_t)r0 * KDIM;
    for (int q = tid; q < 2 * (KDIM / 8); q += 256) {
      int row = (q >= KDIM / 8);
      int g = q - (row ? KDIM / 8 : 0);
      *(bf16x8_t*)(d0 + (size_t)row * KDIM + g * 8) =
          *(const bf16x8_t*)&pr[row][g * 8];
    }
  } else if (blk < NB_FEAT + NB_INIT) {
    int idx = (blk - NB_FEAT) * 256 + tid;             // float4 index
    f32x4_t bv = *(const f32x4_t*)(bias + ((idx * 4) & (N_COLS - 1)));
    *(f32x4_t*)(out + (size_t)idx * 4) = bv;
  } else {
    int g = (blk - NB_FEAT - NB_INIT) * 256 + tid;     // group of 8
    f32x8_t v = *(const f32x8_t*)(w + (size_t)g * 8);
    u32x4_t o;
#pragma unroll
    for (int h = 0; h < 4; ++h) o[h] = pk2(v[2 * h], v[2 * h + 1]);
    *(u32x4_t*)(wb + (size_t)g * 8) = o;
  }
}

// ---------------- bf16 MFMA GEMM: out += feats @ W^T ----------------
// ROUND-1 EXACT structure (94us proven): BM=BN=128, BK=64, 4 waves (2x2),
// split-K=2, single-buffer LDS, 2-barrier loop, global_load_lds(16B) with
// pre-swizzled source so ds_read_b128 is conflict-free.
#define BMT 128
#define BNT 128
#define BKT 64
#define KSTEPS 131   // 8384/64
#define KCUT 66      // split: [0,66) and [66,131)

__global__ __launch_bounds__(256, 2) void gemm_poly(
    const uint16_t* __restrict__ A,   // feats bf16 [B_ROWS][KDIM]
    const uint16_t* __restrict__ W,   // bf16 [N_COLS][KDIM]
    float* __restrict__ out) {
  __shared__ __align__(16) uint16_t sA[BMT * BKT];   // 16 KB
  __shared__ __align__(16) uint16_t sW[BNT * BKT];   // 16 KB

  const int tid  = threadIdx.x;
  const int lane = tid & 63;
  const int wv   = tid >> 6;
  const int wr   = wv >> 1;     // wave row (0..1)
  const int wc   = wv & 1;      // wave col (0..1)
  const int hi   = lane >> 4;   // 0..3
  const int lr   = lane & 15;

  const int b0 = blockIdx.x * BMT;
  const int n0 = blockIdx.y * BNT;
  const int kt0 = (blockIdx.z == 0) ? 0 : KCUT;
  const int kt1 = (blockIdx.z == 0) ? KCUT : KSTEPS;

  // staging geometry: linear LDS offset L = q*4096 + tid*16 -> (row, cb)
  int rowq[4], cbxq[4];
#pragma unroll
  for (int q = 0; q < 4; ++q) {
    int L = q * 4096 + tid * 16;
    int row = L >> 7;          // 128 B per row
    int cb  = L & 127;
    rowq[q] = row;
    cbxq[q] = cb ^ ((row & 7) << 4);   // inverse-swizzled source chunk
  }

  // fragment LDS byte offsets (same XOR on read)
  int offA[4][2], offW[4][2];
#pragma unroll
  for (int f = 0; f < 4; ++f) {
    int rowA = wr * 64 + f * 16 + lr;
    int rowW = wc * 64 + f * 16 + lr;
#pragma unroll
    for (int kh = 0; kh < 2; ++kh) {
      int kb = kh * 64 + hi * 16;
      offA[f][kh] = rowA * 128 + (kb ^ ((rowA & 7) << 4));
      offW[f][kh] = rowW * 128 + (kb ^ ((rowW & 7) << 4));
    }
  }

  f32x4_t acc[4][4];
#pragma unroll
  for (int mf = 0; mf < 4; ++mf)
#pragma unroll
    for (int nf = 0; nf < 4; ++nf) {
      f32x4_t z = {0.f, 0.f, 0.f, 0.f};
      acc[mf][nf] = z;
    }

  const char* Ab = (const char*)A;
  const char* Wb = (const char*)W;

#define STAGE(kt)                                                              \
  {                                                                            \
    _Pragma("unroll")                                                          \
    for (int q = 0; q < 4; ++q) {                                              \
      const char* srcA =                                                       \
          Ab + ((size_t)(b0 + rowq[q]) * KDIM + (kt) * BKT) * 2 + cbxq[q];     \
      async_load16((char*)sA + q * 4096 + tid * 16, srcA);                     \
    }                                                                          \
    _Pragma("unroll")                                                          \
    for (int q = 0; q < 4; ++q) {                                              \
      const char* srcW =                                                       \
          Wb + ((size_t)(n0 + rowq[q]) * KDIM + (kt) * BKT) * 2 + cbxq[q];     \
      async_load16((char*)sW + q * 4096 + tid * 16, srcW);                     \
    }                                                                          \
  }

  STAGE(kt0);
  for (int kt = kt0; kt < kt1; ++kt) {
    __syncthreads();   // staging drained, data visible
    bf16x8_t a[4][2], b[4][2];
#pragma unroll
    for (int mf = 0; mf < 4; ++mf)
#pragma unroll
      for (int kh = 0; kh < 2; ++kh)
        a[mf][kh] = *(const bf16x8_t*)((const char*)sA + offA[mf][kh]);
#pragma unroll
    for (int nf = 0; nf < 4; ++nf)
#pragma unroll
      for (int kh = 0; kh < 2; ++kh)
        b[nf][kh] = *(const bf16x8_t*)((const char*)sW + offW[nf][kh]);
#pragma unroll
    for (int mf = 0; mf < 4; ++mf)
#pragma unroll
      for (int nf = 0; nf < 4; ++nf) {
        acc[mf][nf] = __builtin_amdgcn_mfma_f32_16x16x32_bf16(
            a[mf][0], b[nf][0], acc[mf][nf], 0, 0, 0);
        acc[mf][nf] = __builtin_amdgcn_mfma_f32_16x16x32_bf16(
            a[mf][1], b[nf][1], acc[mf][nf], 0, 0, 0);
      }
    __syncthreads();   // everyone done reading LDS
    if (kt + 1 < kt1) STAGE(kt + 1);
  }

  // epilogue: C/D layout col=lane&15, row=(lane>>4)*4+reg
#pragma unroll
  for (int mf = 0; mf < 4; ++mf) {
    int row = b0 + wr * 64 + mf * 16 + hi * 4;
#pragma unroll
    for (int nf = 0; nf < 4; ++nf) {
      int col = n0 + wc * 64 + nf * 16 + lr;
#pragma unroll
      for (int r = 0; r < 4; ++r) {
        atomicAdd(&out[(size_t)(row + r) * N_COLS + col], acc[mf][nf][r]);
      }
    }
  }
#undef STAGE
}

// ---------------- naive fallback (only if ws too small) ----------------
__global__ void naive_poly(const float* __restrict__ x, const float* __restrict__ w,
                           const float* __restrict__ bias, float* __restrict__ out) {
  size_t o = (size_t)blockIdx.x * 256 + threadIdx.x;
  if (o >= (size_t)B_ROWS * N_COLS) return;
  int n = (int)(o >> 13);
  int b = (int)(o & (B_ROWS - 1));
  const float* xr = x + (size_t)b * D_IN;
  const float* wr = w + (size_t)n * KDIM;
  float acc = bias[n];
  for (int k = 0; k < D_IN; ++k) acc += wr[k] * xr[k];
  int p = D_IN;
  for (int i = 0; i < D_IN; ++i) {
    float xi = xr[i];
    for (int j = i; j < D_IN; ++j) acc += wr[p++] * xi * xr[j];
  }
  out[(size_t)b * N_COLS + n] = acc;
}

extern "C" void kernel_launch(void* const* d_in, const int* in_sizes, int n_in,
                              void* d_out, int out_size, void* d_ws, size_t ws_size,
                              hipStream_t stream) {
  const float* x    = (const float*)d_in[0];
  const float* w    = (const float*)d_in[1];
  const float* bias = (const float*)d_in[2];
  float* out = (float*)d_out;

  if (ws_size < WS_NEED) {   // safety net: correct but slow
    naive_poly<<<(B_ROWS * N_COLS) / 256, 256, 0, stream>>>(x, w, bias, out);
    return;
  }

  char* ws = (char*)d_ws;
  uint16_t* wb  = (uint16_t*)(ws + WBF_OFF);
  uint16_t* fe  = (uint16_t*)(ws + FEA_OFF);

  fused_prep<<<NB_FEAT + NB_INIT + NB_WCNV, 256, 0, stream>>>(x, w, bias, out, wb, fe);
  gemm_poly<<<dim3(B_ROWS / BMT, N_COLS / BNT, 2), 256, 0, stream>>>(fe, wb, out);
}